// Round 4
// baseline (330.989 us; speedup 1.0000x reference)
//
#include <hip/hip_runtime.h>
#include <hip/hip_bf16.h>

// GCN 2-layer forward, fp32 I/O. dinv folded into stored rows:
//   h1' = dinv * (x @ W1),  agg1 = dinv * (h1'[i] + sum_nbr h1'[s])
//   h2' = dinv * (relu(agg1+b1) @ W2),  out = dinv * (h2'[i] + sum h2'[s]) + b2
//
// Gather layer is XCD-feature-chunked: h tables stored chunk-major
// [NCH][N+1][16 feats]; chunk = blockIdx&(NCH-1) pins each 3.2 MB slab to
// one XCD's L2 (h1: 8 chunks -> 1 XCD each; h2: 4 chunks -> 2 XCDs each).
// THIS ROUND (fixing round-3's VALU-issue bound, 10 instr/edge):
//  * k_bcsr counting-sorts nodes by degree per bucket -> rank-ordered
//    slots; waves of 16 equal-degree nodes => no loop divergence.
//  * self-loop and padding are ordinary CSR entries (pad = ZROW = zeroed
//    row N) => pull loops are uniform `for k<pv step 4`, no tail, no deg
//    checks, no self special-case.
//  * 4-lane groups, dwordx2 gathers: ~4 instr/edge total (row-major parity)
//    at 1/3 the HBM traffic.
// Pipeline:
//  1) k_prep: W1,W2 -> bf16 transposed; bcur init; zero ZROWs
//  2) k_bucket: partition packed {src,dloc} by dst>>9 into ebuf
//  3) k_bcsr:  stage -> hist -> degree counting-sort -> padded scan in
//              rank order -> dinv/nord/degr/rpr -> self+pad+edge scatter
//  4) h1' = dinv*(x @ W1) -> bf16 chunk-major     (k_gemm1, MFMA)
//  5) aggb = dinv*(gather-sum h1') chunk-major    (k_pull128)
//  6) h2' = dinv*(relu(aggb+b1) @ W2) chunk-major (k_gemm2, MFMA)
//  7) out = dinv*(gather-sum h2') + b2            (k_pull64)

typedef short short8v __attribute__((ext_vector_type(8)));   // 8 bf16 (4 VGPRs)
typedef float f32x4   __attribute__((ext_vector_type(4)));   // MFMA acc
typedef int   int4v   __attribute__((ext_vector_type(4)));   // dwordx4 index load

#define BSHIFT 9           // bucket = dst >> 9 (span 512 nodes)
#define BSIZE  512
#define CAPSH  14          // per-bucket capacity 16384 (padded mean ~10K, >40 sigma)
#define CAP    (1 << CAPSH)
#define IDXCAP 4096        // staged-index LDS capacity per 64-slot block

// RNE fp32 -> bf16 (finite inputs)
__device__ __forceinline__ short f2bf(float f) {
    unsigned u = __float_as_uint(f);
    return (short)((u + 0x7fffu + ((u >> 16) & 1u)) >> 16);
}
__device__ __forceinline__ unsigned pack2bf(float a, float b) {
    return (unsigned)(unsigned short)f2bf(a) | ((unsigned)(unsigned short)f2bf(b) << 16);
}
__device__ __forceinline__ float bflo(unsigned u) { return __uint_as_float(u << 16); }
__device__ __forceinline__ float bfhi(unsigned u) { return __uint_as_float(u & 0xffff0000u); }

// ---- W prep + bucket-cursor init + ZROW zeroing (one launch) ----
__global__ void k_prep(const float* __restrict__ W1, const float* __restrict__ W2,
                       short* __restrict__ w1t, short* __restrict__ w2t,
                       int* __restrict__ bcur, int nbuck,
                       short* __restrict__ bufH, short* __restrict__ bufH2, int N) {
    int b = blockIdx.x;
    int t = threadIdx.x;
    if (b == gridDim.x - 1) {                 // last block: cursors + ZROWs
        if (t < nbuck) bcur[t] = t << CAPSH;
        size_t np1 = (size_t)N + 1;
        if (t < 128) {                        // h1: 8 chunks x 16 feats
            bufH[((size_t)(t >> 4) * np1 + N) * 16 + (t & 15)] = 0;
        } else if (t < 192) {                 // h2: 4 chunks x 16 feats
            int z = t - 128;
            bufH2[((size_t)(z >> 4) * np1 + N) * 16 + (z & 15)] = 0;
        }
        return;
    }
    int i = b * 256 + t;                      // 96 blocks cover 24576 elems
    if (i < 128 * 128) {
        int n = i >> 7, k = i & 127;
        w1t[i] = f2bf(W1[k * 128 + n]);
    } else {
        int j = i - 128 * 128;
        int n = j >> 7, k = j & 127;
        w2t[j] = f2bf(W2[k * 64 + n]);
    }
}

// ---- partition edges into packed ebuf: entry = (src<<9) | (dst&511) ----
__global__ __launch_bounds__(256) void k_bucket(const int* __restrict__ src,
                                                const int* __restrict__ dst,
                                                int* __restrict__ bcur,
                                                unsigned* __restrict__ ebuf,
                                                int E, int nbuck) {
    __shared__ int sdst[4096];
    __shared__ int ssrc[4096];
    __shared__ int hist[256];
    __shared__ int base[256];
    int t = threadIdx.x;
    int e0 = blockIdx.x * 4096;
    for (int i = t; i < nbuck; i += 256) hist[i] = 0;
    for (int i = 0; i < 16; ++i) {                  // single global read
        int k = i * 256 + t;
        int e = e0 + k;
        sdst[k] = (e < E) ? dst[e] : -1;
        ssrc[k] = (e < E) ? src[e] : 0;
    }
    __syncthreads();
    for (int i = 0; i < 16; ++i) {                  // pass 1: LDS histogram
        int d = sdst[i * 256 + t];
        if (d >= 0) atomicAdd(&hist[d >> BSHIFT], 1);
    }
    __syncthreads();
    for (int b = t; b < nbuck; b += 256) {          // pass 2: reserve chunks
        int c = hist[b];
        base[b] = c ? atomicAdd(&bcur[b], c) : 0;
        hist[b] = 0;
    }
    __syncthreads();
    for (int i = 0; i < 16; ++i) {                  // pass 3: grouped writes
        int k = i * 256 + t;
        int d = sdst[k];
        if (d >= 0) {
            int bk = d >> BSHIFT;
            int off = atomicAdd(&hist[bk], 1);
            ebuf[base[bk] + off] = ((unsigned)ssrc[k] << BSHIFT) | (unsigned)(d & (BSIZE - 1));
        }
    }
}

// ---- per-bucket: stage -> hist -> degree counting-sort -> padded scan in
//      rank order -> dinv/nord/degr/rpr -> self+pad fill -> edge scatter ----
// Row for node (rank r): [self, edges..(arbitrary order).., ZROW pads] with
// total pv = (deg+1+3)&~3 entries; rows laid out in rank order (degree-sorted)
// so pull waves of 16 consecutive slots have near-equal trip counts.
__global__ __launch_bounds__(BSIZE) void k_bcsr(const unsigned* __restrict__ ebuf,
                                                const int* __restrict__ bcur,
                                                float* __restrict__ dinv,
                                                int* __restrict__ nord,
                                                int* __restrict__ degr,
                                                int* __restrict__ rpr,
                                                unsigned* __restrict__ csr4, int n) {
    __shared__ unsigned edges[CAP];    // 64 KB
    __shared__ int hist[BSIZE];
    __shared__ int s[BSIZE];
    __shared__ int cur[BSIZE];
    int b = blockIdx.x;
    int t = threadIdx.x;
    hist[t] = 0;
    __syncthreads();
    int base = b << CAPSH;
    int cnt  = bcur[b] - base;
    int lo = b << BSHIFT;
    for (int k = t; k < cnt; k += BSIZE) {          // stage + LDS hist
        unsigned e = ebuf[base + k];
        edges[k] = e;
        atomicAdd(&hist[e & (BSIZE - 1)], 1);
    }
    __syncthreads();
    int v = hist[t];                                // in-degree of local node t
    int node = lo + t;
    bool valid = node < n;
    __syncthreads();                                // all hist reads done
    hist[t] = 0;                                    // reuse as degree histogram
    __syncthreads();
    int key = valid ? min(v, BSIZE - 1) : 0;
    atomicAdd(&hist[key], 1);
    __syncthreads();
    s[t] = hist[t];
    __syncthreads();
    for (int off = 1; off < BSIZE; off <<= 1) {     // inclusive scan of deg-hist
        int add = (t >= off) ? s[t - off] : 0;
        __syncthreads();
        s[t] += add;
        __syncthreads();
    }
    cur[t] = 0;                                     // reuse as per-degree cursor
    __syncthreads();
    int r = (s[key] - hist[key]) + atomicAdd(&cur[key], 1);   // rank (permutation)
    __syncthreads();                                // s reads done before reuse
    int pv = valid ? ((v + 4) & ~3) : 0;            // self + pad, 16B granules
    s[r] = pv;
    __syncthreads();
    for (int off = 1; off < BSIZE; off <<= 1) {     // inclusive scan in rank order
        int add = (t >= off) ? s[t - off] : 0;
        __syncthreads();
        s[t] += add;
        __syncthreads();
    }
    int rp = base + s[r] - pv;                      // row start (16B aligned)
    cur[t] = rp + 1;                                // edges go after the self slot
    int slot = (b << BSHIFT) + r;
    if (valid) {
        dinv[node] = rsqrtf((float)(v + 1));
        nord[slot] = node;
        degr[slot] = v;
        rpr[slot]  = rp;
        csr4[rp] = (unsigned)node;                  // self entry
        for (int j = v + 1; j < pv; ++j) csr4[rp + j] = (unsigned)n;  // ZROW pads
    } else {
        nord[slot] = -1;
        degr[slot] = 0;
        rpr[slot]  = rp;
    }
    __syncthreads();
    for (int k = t; k < cnt; k += BSIZE) {          // scatter src -> csr4
        unsigned e = edges[k];
        int pos = atomicAdd(&cur[e & (BSIZE - 1)], 1);
        csr4[pos] = e >> BSHIFT;
    }
}

// ---- MFMA GEMM1: h1'[64rows,128] = dinv*(bf16(x) @ bf16(W1)) ----
// Output CHUNK-MAJOR: h[chunk][(N+1) rows][16 feats], chunk = feat>>4.
#define LDP 136
__global__ __launch_bounds__(256) void k_gemm1(const float* __restrict__ x,
                                               const short* __restrict__ w1t,
                                               const float* __restrict__ dinv,
                                               short* __restrict__ h, int nrows) {
    __shared__ short xs[64 * LDP];
    __shared__ short wt[128 * LDP];
    int t = threadIdx.x;
    int row0 = blockIdx.x * 64;
    for (int i = 0; i < 16; ++i) {
        int idx = t + i * 256;
        int r = idx >> 5, c4 = idx & 31;
        float4 v = make_float4(0.f, 0.f, 0.f, 0.f);
        if (row0 + r < nrows) v = ((const float4*)x)[(size_t)(row0 + r) * 32 + c4];
        short4 o = make_short4(f2bf(v.x), f2bf(v.y), f2bf(v.z), f2bf(v.w));
        *(short4*)&xs[r * LDP + c4 * 4] = o;
    }
    for (int i = 0; i < 16; ++i) {
        int idx = t + i * 256;
        int n = idx >> 5, c4 = idx & 31;
        *(short4*)&wt[n * LDP + c4 * 4] = ((const short4*)w1t)[idx];
    }
    __syncthreads();
    int wave = t >> 6, lane = t & 63;
    int quad = lane >> 4, c = lane & 15;
    int m0 = wave * 16;
    f32x4 acc[8] = {};
    #pragma unroll
    for (int kc = 0; kc < 4; ++kc) {
        short8v a = *(const short8v*)&xs[(m0 + c) * LDP + kc * 32 + quad * 8];
        #pragma unroll
        for (int nt = 0; nt < 8; ++nt) {
            short8v b = *(const short8v*)&wt[(nt * 16 + c) * LDP + kc * 32 + quad * 8];
            acc[nt] = __builtin_amdgcn_mfma_f32_16x16x32_bf16(a, b, acc[nt], 0, 0, 0);
        }
    }
    size_t slab = ((size_t)nrows + 1) * 16;         // shorts per chunk slab
    #pragma unroll
    for (int r = 0; r < 4; ++r) {
        int row = row0 + m0 + quad * 4 + r;
        if (row < nrows) {
            float dr = dinv[row];                   // fold norm into stored row
            #pragma unroll
            for (int nt = 0; nt < 8; ++nt)
                h[(size_t)nt * slab + (size_t)row * 16 + c] = f2bf(acc[nt][r] * dr);
        }
    }
}

// ---- MFMA GEMM2: h2'[64rows,64] = dinv*(bf16(relu(aggb+b1)) @ bf16(W2)) ----
// aggb CHUNK-MAJOR bf16x2 [8][(N+1)][8]; h2 output CHUNK-MAJOR [4][(N+1)][16].
__global__ __launch_bounds__(256) void k_gemm2(const unsigned* __restrict__ aggb,
                                               const float* __restrict__ b1,
                                               const short* __restrict__ w2t,
                                               const float* __restrict__ dinv,
                                               short* __restrict__ h2, int nrows) {
    __shared__ short xs[64 * LDP];
    __shared__ short wt[64 * LDP];
    int t = threadIdx.x;
    int row0 = blockIdx.x * 64;
    size_t slab8 = ((size_t)nrows + 1) * 8;           // uints per h1-chunk slab
    for (int i = 0; i < 16; ++i) {                    // 64 rows x 64 bf16-pairs
        int idx = t + i * 256;
        int r = idx >> 6, cp = idx & 63;
        unsigned o = 0;
        if (row0 + r < nrows) {
            unsigned u = aggb[(size_t)(cp >> 3) * slab8 + (size_t)(row0 + r) * 8 + (cp & 7)];
            float2 bb = ((const float2*)b1)[cp];
            float vx = fmaxf(bflo(u) + bb.x, 0.f);
            float vy = fmaxf(bfhi(u) + bb.y, 0.f);
            o = pack2bf(vx, vy);
        }
        *(unsigned*)&xs[r * LDP + cp * 2] = o;
    }
    for (int i = 0; i < 8; ++i) {
        int idx = t + i * 256;
        int n = idx >> 5, c4 = idx & 31;
        *(short4*)&wt[n * LDP + c4 * 4] = ((const short4*)w2t)[idx];
    }
    __syncthreads();
    int wave = t >> 6, lane = t & 63;
    int quad = lane >> 4, c = lane & 15;
    int m0 = wave * 16;
    f32x4 acc[4] = {};
    #pragma unroll
    for (int kc = 0; kc < 4; ++kc) {
        short8v av = *(const short8v*)&xs[(m0 + c) * LDP + kc * 32 + quad * 8];
        #pragma unroll
        for (int nt = 0; nt < 4; ++nt) {
            short8v b = *(const short8v*)&wt[(nt * 16 + c) * LDP + kc * 32 + quad * 8];
            acc[nt] = __builtin_amdgcn_mfma_f32_16x16x32_bf16(av, b, acc[nt], 0, 0, 0);
        }
    }
    size_t slab16 = ((size_t)nrows + 1) * 16;         // shorts per h2-chunk slab
    #pragma unroll
    for (int r = 0; r < 4; ++r) {
        int row = row0 + m0 + quad * 4 + r;
        if (row < nrows) {
            float dr = dinv[row];
            #pragma unroll
            for (int nt = 0; nt < 4; ++nt)
                h2[(size_t)nt * slab16 + (size_t)row * 16 + c] = f2bf(acc[nt][r] * dr);
        }
    }
}

// pull 128 feats, chunked + degree-sorted slots + uniform padded rows:
//   aggb[c][node] = bf16( dinv * sum over padded row (incl self, ZROW pads) )
// Block = chunk (blockIdx&7) x 64 consecutive rank slots. 4-lane groups,
// dwordx2 gathers, indices LDS-staged via bulk coalesced NT loads.
__global__ __launch_bounds__(256) void k_pull128(const unsigned* __restrict__ h,   // [8][(n+1)][8] bf16x2
                                                 const int* __restrict__ nord,
                                                 const int* __restrict__ degr,
                                                 const int* __restrict__ rpr,
                                                 const unsigned* __restrict__ csr4,
                                                 unsigned* __restrict__ aggb,      // [8][(n+1)][8]
                                                 int n) {
    __shared__ int sIdx[IDXCAP];
    __shared__ int sN[64];
    __shared__ int sV[64];
    __shared__ int sRP[64];
    int chunk = blockIdx.x & 7;
    int sb    = blockIdx.x >> 3;
    int s0 = sb * 64;
    int t = threadIdx.x;
    if (t < 64) {
        sN[t]  = __builtin_nontemporal_load(&nord[s0 + t]);
        sV[t]  = __builtin_nontemporal_load(&degr[s0 + t]);
        sRP[t] = __builtin_nontemporal_load(&rpr[s0 + t]);
    }
    __syncthreads();
    int rpBeg = sRP[0];
    int pvL = (sN[63] >= 0) ? ((sV[63] + 4) & ~3) : 0;
    int range = sRP[63] + pvL - rpBeg;
    bool fast = (range <= IDXCAP);
    if (fast) {
        for (int j = t * 4; j < range; j += 1024) {
            int4v vv = __builtin_nontemporal_load((const int4v*)(csr4 + rpBeg + j));
            *(int4v*)&sIdx[j] = vv;
        }
    }
    __syncthreads();

    int lane = t & 63;
    int wv   = t >> 6;                    // 0..3
    int grp  = lane >> 2;                 // 0..15 (4-lane node groups)
    int sub  = lane & 3;                  // 2 uints (4 feats) per lane
    int li = wv * 16 + grp;               // local slot 0..63
    int node = sN[li];
    bool alive = node >= 0;
    int v  = sV[li];
    int pv = alive ? ((v + 4) & ~3) : 0;
    int off = sRP[li] - rpBeg;
    const unsigned* hc = h + (size_t)chunk * (((size_t)n + 1) * 8);
    float a0 = 0.f, a1 = 0.f, a2 = 0.f, a3 = 0.f;
    if (fast) {
        for (int k = 0; k < pv; k += 4) {
            int o = off + k;
            int x0 = sIdx[o], x1 = sIdx[o + 1], x2 = sIdx[o + 2], x3 = sIdx[o + 3];
            uint2 g0 = *(const uint2*)&hc[(x0 << 3) + (sub << 1)];
            uint2 g1 = *(const uint2*)&hc[(x1 << 3) + (sub << 1)];
            uint2 g2 = *(const uint2*)&hc[(x2 << 3) + (sub << 1)];
            uint2 g3 = *(const uint2*)&hc[(x3 << 3) + (sub << 1)];
            a0 += bflo(g0.x); a1 += bfhi(g0.x); a2 += bflo(g0.y); a3 += bfhi(g0.y);
            a0 += bflo(g1.x); a1 += bfhi(g1.x); a2 += bflo(g1.y); a3 += bfhi(g1.y);
            a0 += bflo(g2.x); a1 += bfhi(g2.x); a2 += bflo(g2.y); a3 += bfhi(g2.y);
            a0 += bflo(g3.x); a1 += bfhi(g3.x); a2 += bflo(g3.y); a3 += bfhi(g3.y);
        }
    } else {                              // rare fallback: global idx reads
        for (int k = 0; k < pv; k += 4) {
            int o = rpBeg + off + k;
            int x0 = csr4[o], x1 = csr4[o + 1], x2 = csr4[o + 2], x3 = csr4[o + 3];
            uint2 g0 = *(const uint2*)&hc[(x0 << 3) + (sub << 1)];
            uint2 g1 = *(const uint2*)&hc[(x1 << 3) + (sub << 1)];
            uint2 g2 = *(const uint2*)&hc[(x2 << 3) + (sub << 1)];
            uint2 g3 = *(const uint2*)&hc[(x3 << 3) + (sub << 1)];
            a0 += bflo(g0.x); a1 += bfhi(g0.x); a2 += bflo(g0.y); a3 += bfhi(g0.y);
            a0 += bflo(g1.x); a1 += bfhi(g1.x); a2 += bflo(g1.y); a3 += bfhi(g1.y);
            a0 += bflo(g2.x); a1 += bfhi(g2.x); a2 += bflo(g2.y); a3 += bfhi(g2.y);
            a0 += bflo(g3.x); a1 += bfhi(g3.x); a2 += bflo(g3.y); a3 += bfhi(g3.y);
        }
    }
    if (alive) {
        float di = rsqrtf((float)(v + 1));          // == bcsr's dinv bit-identically
        unsigned* ab = aggb + (size_t)chunk * (((size_t)n + 1) * 8);
        uint2 o2;
        o2.x = pack2bf(a0 * di, a1 * di);
        o2.y = pack2bf(a2 * di, a3 * di);
        *(uint2*)&ab[(node << 3) + (sub << 1)] = o2;
    }
}

// pull 64 feats, same structure with 4 chunks (2 XCDs per chunk):
//   out[node] = dinv * sum(padded row of h2') + b2
__global__ __launch_bounds__(256) void k_pull64(const unsigned* __restrict__ h2,   // [4][(n+1)][8] bf16x2
                                                const int* __restrict__ nord,
                                                const int* __restrict__ degr,
                                                const int* __restrict__ rpr,
                                                const unsigned* __restrict__ csr4,
                                                const float* __restrict__ b2,
                                                float* __restrict__ out, int n) {
    __shared__ int sIdx[IDXCAP];
    __shared__ int sN[64];
    __shared__ int sV[64];
    __shared__ int sRP[64];
    int chunk = blockIdx.x & 3;
    int sb    = blockIdx.x >> 2;
    int s0 = sb * 64;
    int t = threadIdx.x;
    if (t < 64) {
        sN[t]  = __builtin_nontemporal_load(&nord[s0 + t]);
        sV[t]  = __builtin_nontemporal_load(&degr[s0 + t]);
        sRP[t] = __builtin_nontemporal_load(&rpr[s0 + t]);
    }
    __syncthreads();
    int rpBeg = sRP[0];
    int pvL = (sN[63] >= 0) ? ((sV[63] + 4) & ~3) : 0;
    int range = sRP[63] + pvL - rpBeg;
    bool fast = (range <= IDXCAP);
    if (fast) {
        for (int j = t * 4; j < range; j += 1024) {
            int4v vv = __builtin_nontemporal_load((const int4v*)(csr4 + rpBeg + j));
            *(int4v*)&sIdx[j] = vv;
        }
    }
    __syncthreads();

    int lane = t & 63;
    int wv   = t >> 6;
    int grp  = lane >> 2;
    int sub  = lane & 3;
    int li = wv * 16 + grp;
    int node = sN[li];
    bool alive = node >= 0;
    int v  = sV[li];
    int pv = alive ? ((v + 4) & ~3) : 0;
    int off = sRP[li] - rpBeg;
    const unsigned* hc = h2 + (size_t)chunk * (((size_t)n + 1) * 8);
    float a0 = 0.f, a1 = 0.f, a2 = 0.f, a3 = 0.f;
    if (fast) {
        for (int k = 0; k < pv; k += 4) {
            int o = off + k;
            int x0 = sIdx[o], x1 = sIdx[o + 1], x2 = sIdx[o + 2], x3 = sIdx[o + 3];
            uint2 g0 = *(const uint2*)&hc[(x0 << 3) + (sub << 1)];
            uint2 g1 = *(const uint2*)&hc[(x1 << 3) + (sub << 1)];
            uint2 g2 = *(const uint2*)&hc[(x2 << 3) + (sub << 1)];
            uint2 g3 = *(const uint2*)&hc[(x3 << 3) + (sub << 1)];
            a0 += bflo(g0.x); a1 += bfhi(g0.x); a2 += bflo(g0.y); a3 += bfhi(g0.y);
            a0 += bflo(g1.x); a1 += bfhi(g1.x); a2 += bflo(g1.y); a3 += bfhi(g1.y);
            a0 += bflo(g2.x); a1 += bfhi(g2.x); a2 += bflo(g2.y); a3 += bfhi(g2.y);
            a0 += bflo(g3.x); a1 += bfhi(g3.x); a2 += bflo(g3.y); a3 += bfhi(g3.y);
        }
    } else {
        for (int k = 0; k < pv; k += 4) {
            int o = rpBeg + off + k;
            int x0 = csr4[o], x1 = csr4[o + 1], x2 = csr4[o + 2], x3 = csr4[o + 3];
            uint2 g0 = *(const uint2*)&hc[(x0 << 3) + (sub << 1)];
            uint2 g1 = *(const uint2*)&hc[(x1 << 3) + (sub << 1)];
            uint2 g2 = *(const uint2*)&hc[(x2 << 3) + (sub << 1)];
            uint2 g3 = *(const uint2*)&hc[(x3 << 3) + (sub << 1)];
            a0 += bflo(g0.x); a1 += bfhi(g0.x); a2 += bflo(g0.y); a3 += bfhi(g0.y);
            a0 += bflo(g1.x); a1 += bfhi(g1.x); a2 += bflo(g1.y); a3 += bfhi(g1.y);
            a0 += bflo(g2.x); a1 += bfhi(g2.x); a2 += bflo(g2.y); a3 += bfhi(g2.y);
            a0 += bflo(g3.x); a1 += bfhi(g3.x); a2 += bflo(g3.y); a3 += bfhi(g3.y);
        }
    }
    if (alive) {
        float di = rsqrtf((float)(v + 1));
        int f0 = chunk * 16 + sub * 4;
        float4 bb = *(const float4*)&b2[f0];
        float4 o;
        o.x = a0 * di + bb.x;
        o.y = a1 * di + bb.y;
        o.z = a2 * di + bb.z;
        o.w = a3 * di + bb.w;
        *(float4*)&out[(size_t)node * 64 + f0] = o;
    }
}

extern "C" void kernel_launch(void* const* d_in, const int* in_sizes, int n_in,
                              void* d_out, int out_size, void* d_ws, size_t ws_size,
                              hipStream_t stream) {
    const float* x  = (const float*)d_in[0];
    const int*   ei = (const int*)d_in[1];
    const float* W1 = (const float*)d_in[2];
    const float* b1 = (const float*)d_in[3];
    const float* W2 = (const float*)d_in[4];
    const float* b2 = (const float*)d_in[5];
    float* out = (float*)d_out;

    const int N = in_sizes[0] / 128;
    const int E = in_sizes[1] / 2;
    const int* src = ei;
    const int* dst = ei + E;
    const int nbuck = (N + BSIZE - 1) >> BSHIFT;        // 196 for N=100000
    const int nslot = nbuck << BSHIFT;                  // rank slots (mult of 512)
    const size_t capE = (size_t)nbuck << CAPSH;         // padded edge capacity
    const size_t np1 = (size_t)N + 1;

    float* dinv     = (float*)d_ws;                     // N
    int*   bcur     = (int*)(dinv + N);                 // 256
    int*   nord     = bcur + 256;                       // nslot (node per rank slot)
    int*   degr     = nord + nslot;                     // nslot
    int*   rpr      = degr + nslot;                     // nslot
    short* w1t      = (short*)(rpr + nslot);            // 128*128
    short* w2t      = w1t + 128 * 128;                  // 64*128
    unsigned* csr4  = (unsigned*)(w2t + 64 * 128);      // capE (12.8 MB)
    short* bufH     = (short*)(csr4 + capE);            // 8*(N+1)*16 bf16 (h1')
    short* bufH2    = bufH + 8 * np1 * 16;              // 4*(N+1)*16 bf16 (h2')
    unsigned* aggb  = (unsigned*)(bufH2 + 4 * np1 * 16); // 8*(N+1)*8 bf16x2 (agg1)
    unsigned* ebuf  = aggb;                             // capE uints; aliases aggb
                                                        // (ebuf dead before pull128
                                                        //  writes aggb; prep only
                                                        //  touches bufH/bufH2)

    const int ntile = (E + 4095) / 4096;
    const int nsb = nslot / 64;                         // 64-slot blocks

    // ---- weight prep + bucket cursor init + ZROW zeroing ----
    k_prep<<<97, 256, 0, stream>>>(W1, W2, w1t, w2t, bcur, nbuck, bufH, bufH2, N);

    // ---- bucketed CSR build (degree-sorted, self+pad folded in) ----
    k_bucket<<<ntile, 256, 0, stream>>>(src, dst, bcur, ebuf, E, nbuck);
    k_bcsr<<<nbuck, BSIZE, 0, stream>>>(ebuf, bcur, dinv, nord, degr, rpr, csr4, N);

    // ---- layer 1 ----
    k_gemm1<<<(N + 63) / 64, 256, 0, stream>>>(x, w1t, dinv, bufH, N);
    k_pull128<<<8 * nsb, 256, 0, stream>>>((const unsigned*)bufH, nord, degr, rpr, csr4, aggb, N);

    // ---- layer 2 ----
    k_gemm2<<<(N + 63) / 64, 256, 0, stream>>>(aggb, b1, w2t, dinv, bufH2, N);
    k_pull64<<<4 * nsb, 256, 0, stream>>>((const unsigned*)bufH2, nord, degr, rpr, csr4, b2, out, N);
}